// Round 10
// baseline (89.055 us; speedup 1.0000x reference)
//
#include <hip/hip_runtime.h>
#include <hip/hip_fp16.h>
#include <math.h>

constexpr int D = 64;           // D_IN == D_OUT == 64
constexpr int BNODES = 128;     // nodes per bucket
constexpr int BSHIFT = 7;
constexpr int BSTRIDE = 3072;   // fixed ebuf capacity per bucket (Poisson(2048) tail ~0)
constexpr int PCHUNK = 4096;    // edges per partition block
constexpr int NB_MAX = 1024;    // max buckets (N <= 131072)

typedef _Float16 half8 __attribute__((ext_vector_type(8)));
typedef float floatx4 __attribute__((ext_vector_type(4)));

// bcur[j] = j*BSTRIDE; Wt[j][k] = (f16) W[k][j]
__global__ __launch_bounds__(256) void k_init(const float* __restrict__ W,
                                              __half* __restrict__ Wt,
                                              int* __restrict__ bcur, int NB) {
    const int i = blockIdx.x * 256 + threadIdx.x;
    if (i < NB) bcur[i] = i * BSTRIDE;
    if (i < D * D) {
        const int j = i >> 6;
        const int k = i & 63;
        Wt[i] = __float2half(W[k * D + j]);
    }
}

// coarse partition into fixed-stride bucket segments; int4-vectorized edge reads.
__global__ __launch_bounds__(512) void k_partition(
        const int* __restrict__ ei, int* __restrict__ bcur,
        unsigned* __restrict__ ebuf, int E, int NB) {
    __shared__ int lh[NB_MAX];
    __shared__ int lb[NB_MAX];
    __shared__ int cc[PCHUNK];     // 16 KB c-cache
    const int t = threadIdx.x;
    for (int j = t; j < NB; j += 512) lh[j] = 0;
    __syncthreads();
    const int e0 = blockIdx.x * PCHUNK;
    const int e1 = min(e0 + PCHUNK, E);
    const bool full = (e1 - e0 == PCHUNK);

    if (full) {
        const int4* cp = reinterpret_cast<const int4*>(ei + E + e0);
        const int4 ca = cp[t];
        const int4 cb = cp[t + 512];
        reinterpret_cast<int4*>(cc)[t]       = ca;
        reinterpret_cast<int4*>(cc)[t + 512] = cb;
        atomicAdd(&lh[ca.x >> BSHIFT], 1); atomicAdd(&lh[ca.y >> BSHIFT], 1);
        atomicAdd(&lh[ca.z >> BSHIFT], 1); atomicAdd(&lh[ca.w >> BSHIFT], 1);
        atomicAdd(&lh[cb.x >> BSHIFT], 1); atomicAdd(&lh[cb.y >> BSHIFT], 1);
        atomicAdd(&lh[cb.z >> BSHIFT], 1); atomicAdd(&lh[cb.w >> BSHIFT], 1);
    } else {
        for (int e = e0 + t; e < e1; e += 512) {
            const int c = ei[E + e];
            cc[e - e0] = c;
            atomicAdd(&lh[c >> BSHIFT], 1);
        }
    }
    __syncthreads();
    for (int j = t; j < NB; j += 512) {
        const int n = lh[j];
        lb[j] = n ? atomicAdd(&bcur[j], n) : 0;
        lh[j] = 0;
    }
    __syncthreads();

    if (full) {
        const int4* rp = reinterpret_cast<const int4*>(ei + e0);
        const int4 ra = rp[t];
        const int4 rb = rp[t + 512];
        const int r8[8] = {ra.x, ra.y, ra.z, ra.w, rb.x, rb.y, rb.z, rb.w};
#pragma unroll
        for (int k = 0; k < 8; ++k) {
            const int ci = (k < 4) ? (4 * t + k) : (2048 + 4 * t + (k - 4));
            const int c = cc[ci];
            const int bkt = c >> BSHIFT;
            const int rank = atomicAdd(&lh[bkt], 1);
            const int pos = lb[bkt] + rank;
            if (pos < (bkt + 1) * BSTRIDE)
                ebuf[pos] = ((unsigned)r8[k] << BSHIFT) | (unsigned)(c & (BNODES - 1));
        }
    } else {
        for (int e = e0 + t; e < e1; e += 512) {
            const int r = ei[e];
            const int c = cc[e - e0];
            const int bkt = c >> BSHIFT;
            const int rank = atomicAdd(&lh[bkt], 1);
            const int pos = lb[bkt] + rank;
            if (pos < (bkt + 1) * BSTRIDE)
                ebuf[pos] = ((unsigned)r << BSHIFT) | (unsigned)(c & (BNODES - 1));
        }
    }
}

// fused per-bucket degree hist + MFMA GEMM: gh0/gh1(fp16 halves) = dinv * (x@W)
// One block per bucket (512 thr = 8 waves x 16-node tiles). No global cnt array.
__global__ __launch_bounds__(512) void k_gemm_fused(
        const float* __restrict__ x, const __half* __restrict__ Wt,
        const unsigned* __restrict__ ebuf, const int* __restrict__ bcur,
        __half* __restrict__ gh0, __half* __restrict__ gh1, int N) {
    __shared__ int lh[BNODES];
    const int j = blockIdx.x;
    const int t = threadIdx.x;
    const int base = j << BSHIFT;
    const int s0 = j * BSTRIDE;
    const int s1 = min(bcur[j], s0 + BSTRIDE);

    if (t < BNODES) lh[t] = 0;
    __syncthreads();
    for (int i = s0 + t; i < s1; i += 512)
        atomicAdd(&lh[ebuf[i] & (BNODES - 1)], 1);
    __syncthreads();

    const int wave = t >> 6;
    const int node16 = base + wave * 16;
    if (node16 >= N) return;          // N % 16 == 0, wave-aligned guard
    const int lane = t & 63;
    const int r16  = lane & 15;
    const int kq   = lane >> 4;

    const _Float16* wt = (const _Float16*)Wt;
    half8 bf[4][2];
#pragma unroll
    for (int jt = 0; jt < 4; ++jt)
#pragma unroll
        for (int s = 0; s < 2; ++s)
            bf[jt][s] = *(const half8*)(wt + (jt * 16 + r16) * D + s * 32 + kq * 8);

    half8 af[2];
#pragma unroll
    for (int s = 0; s < 2; ++s) {
        const float4* xp = reinterpret_cast<const float4*>(
            x + (size_t)(node16 + r16) * D + s * 32 + kq * 8);
        const float4 x0 = xp[0];
        const float4 x1 = xp[1];
        half8 a;
        a[0] = (_Float16)x0.x; a[1] = (_Float16)x0.y;
        a[2] = (_Float16)x0.z; a[3] = (_Float16)x0.w;
        a[4] = (_Float16)x1.x; a[5] = (_Float16)x1.y;
        a[6] = (_Float16)x1.z; a[7] = (_Float16)x1.w;
        af[s] = a;
    }

    floatx4 acc[4];
#pragma unroll
    for (int jt = 0; jt < 4; ++jt) {
        acc[jt] = (floatx4){0.f, 0.f, 0.f, 0.f};
        acc[jt] = __builtin_amdgcn_mfma_f32_16x16x32_f16(af[0], bf[jt][0], acc[jt], 0, 0, 0);
        acc[jt] = __builtin_amdgcn_mfma_f32_16x16x32_f16(af[1], bf[jt][1], acc[jt], 0, 0, 0);
    }

#pragma unroll
    for (int r = 0; r < 4; ++r) {
        const int nl = wave * 16 + kq * 4 + r;
        const int node = base + nl;
        const float dinv = rsqrtf((float)(lh[nl] + 1));
#pragma unroll
        for (int jt = 0; jt < 2; ++jt)
            gh0[(size_t)node * 32 + jt * 16 + r16] = __float2half(acc[jt][r] * dinv);
#pragma unroll
        for (int jt = 2; jt < 4; ++jt)
            gh1[(size_t)node * 32 + (jt - 2) * 16 + r16] = __float2half(acc[jt][r] * dinv);
    }
}

// fused per-bucket: LDS CSR build, then ONE 4-lane group per node per phase
// (4 lanes x 16B = 64B half-row). Two phases halve the gather working set.
__global__ __launch_bounds__(512) void k_breduce(
        const unsigned* __restrict__ ebuf, const int* __restrict__ bcur,
        const __half* __restrict__ gh0, const __half* __restrict__ gh1,
        const float* __restrict__ b, float* __restrict__ out, int N) {
    __shared__ int srcLDS[BSTRIDE];   // 12 KB
    __shared__ int lh[BNODES];
    __shared__ int st[BNODES];
    __shared__ int lcur[BNODES];
    const int j = blockIdx.x;
    const int t = threadIdx.x;
    const int s0 = j * BSTRIDE;
    const int s1 = min(bcur[j], s0 + BSTRIDE);
    const int base = j << BSHIFT;
    const int nn = min(BNODES, N - base);

    if (t < BNODES) lh[t] = 0;
    __syncthreads();
    for (int i = s0 + t; i < s1; i += 512)
        atomicAdd(&lh[ebuf[i] & (BNODES - 1)], 1);
    __syncthreads();
    if (t < BNODES) st[t] = lh[t];
    __syncthreads();
    for (int off = 1; off < BNODES; off <<= 1) {
        int y = 0;
        if (t < BNODES && t >= off) y = st[t - off];
        __syncthreads();
        if (t < BNODES && t >= off) st[t] += y;
        __syncthreads();
    }
    if (t < BNODES) {
        const int s = st[t] - lh[t];    // exclusive start (bucket-local)
        st[t] = s;
        lcur[t] = s;
    }
    __syncthreads();
    for (int i = s0 + t; i < s1; i += 512) {
        const unsigned code = ebuf[i];
        const int c = code & (BNODES - 1);
        const int rank = atomicAdd(&lcur[c], 1);
        srcLDS[rank] = (int)(code >> BSHIFT);
    }
    __syncthreads();

    const int g  = t >> 2;        // node 0..127
    const int fl = t & 3;         // 16B chunk of the 64B half-row
    if (g >= nn) return;

    const int node = base + g;
    const int start = st[g];
    const int num = lh[g];
    const float dinv = rsqrtf((float)(num + 1));
    const float4* b4 = reinterpret_cast<const float4*>(b);
    float4* o4 = reinterpret_cast<float4*>(out);
    const __half2 z = __float2half2_rn(0.f);

#pragma unroll
    for (int phase = 0; phase < 2; ++phase) {
        const uint4* gp = reinterpret_cast<const uint4*>(phase ? gh1 : gh0);

        // self-loop seed
        const uint4 su = gp[(size_t)node * 4 + fl];
        __half2 a0 = *(const __half2*)&su.x;
        __half2 a1 = *(const __half2*)&su.y;
        __half2 a2 = *(const __half2*)&su.z;
        __half2 a3 = *(const __half2*)&su.w;
        __half2 c0 = z, c1 = z, c2 = z, c3 = z;

        int i = start;
        const int end = start + num;
        for (; i + 2 <= end; i += 2) {      // 2 edges in flight
            const int r0 = srcLDS[i];
            const int r1 = srcLDS[i + 1];
            const uint4 u0 = gp[(size_t)r0 * 4 + fl];
            const uint4 u1 = gp[(size_t)r1 * 4 + fl];
            a0 = __hadd2(a0, *(const __half2*)&u0.x);
            a1 = __hadd2(a1, *(const __half2*)&u0.y);
            a2 = __hadd2(a2, *(const __half2*)&u0.z);
            a3 = __hadd2(a3, *(const __half2*)&u0.w);
            c0 = __hadd2(c0, *(const __half2*)&u1.x);
            c1 = __hadd2(c1, *(const __half2*)&u1.y);
            c2 = __hadd2(c2, *(const __half2*)&u1.z);
            c3 = __hadd2(c3, *(const __half2*)&u1.w);
        }
        if (i < end) {
            const int r = srcLDS[i];
            const uint4 u = gp[(size_t)r * 4 + fl];
            a0 = __hadd2(a0, *(const __half2*)&u.x);
            a1 = __hadd2(a1, *(const __half2*)&u.y);
            a2 = __hadd2(a2, *(const __half2*)&u.z);
            a3 = __hadd2(a3, *(const __half2*)&u.w);
        }
        a0 = __hadd2(a0, c0);
        a1 = __hadd2(a1, c1);
        a2 = __hadd2(a2, c2);
        a3 = __hadd2(a3, c3);

        const float2 f0 = __half22float2(a0);
        const float2 f1 = __half22float2(a1);
        const float2 f2 = __half22float2(a2);
        const float2 f3 = __half22float2(a3);
        const int ob = phase * 8 + fl * 2;   // float4 index of output cols
        const float4 bb0 = b4[ob];
        const float4 bb1 = b4[ob + 1];
        float4 o0, o1;
        o0.x = fmaf(dinv, f0.x, bb0.x); o0.y = fmaf(dinv, f0.y, bb0.y);
        o0.z = fmaf(dinv, f1.x, bb0.z); o0.w = fmaf(dinv, f1.y, bb0.w);
        o1.x = fmaf(dinv, f2.x, bb1.x); o1.y = fmaf(dinv, f2.y, bb1.y);
        o1.z = fmaf(dinv, f3.x, bb1.z); o1.w = fmaf(dinv, f3.y, bb1.w);
        o4[(size_t)node * 16 + ob]     = o0;
        o4[(size_t)node * 16 + ob + 1] = o1;
    }
}

extern "C" void kernel_launch(void* const* d_in, const int* in_sizes, int n_in,
                              void* d_out, int out_size, void* d_ws, size_t ws_size,
                              hipStream_t stream) {
    const float* x  = (const float*)d_in[0];
    const int*   ei = (const int*)d_in[1];
    const float* W  = (const float*)d_in[2];
    const float* b  = (const float*)d_in[3];
    float* out = (float*)d_out;

    const int N = in_sizes[0] / D;     // 100000
    const int E = in_sizes[1] / 2;     // 1600000
    const int NB = (N + BNODES - 1) >> BSHIFT;   // 782
    const int blocksP = (E + PCHUNK - 1) / PCHUNK;

    // ws layout (16B-aligned sections)
    __half*   gh0  = (__half*)d_ws;                     // N*32 halves (6.4 MB)
    __half*   gh1  = gh0 + (size_t)N * 32;              // N*32 halves (6.4 MB)
    __half*   Wt   = gh1 + (size_t)N * 32;              // 4096 halves (8 KB)
    unsigned* ebuf = (unsigned*)(Wt + D * D);           // NB*BSTRIDE (9.6 MB)
    int*      bcur = (int*)(ebuf + (size_t)NB * BSTRIDE); // NB

    k_init      <<<16, 256, 0, stream>>>(W, Wt, bcur, NB);
    k_partition <<<blocksP, 512, 0, stream>>>(ei, bcur, ebuf, E, NB);
    k_gemm_fused<<<NB, 512, 0, stream>>>(x, Wt, ebuf, bcur, gh0, gh1, N);
    k_breduce   <<<NB, 512, 0, stream>>>(ebuf, bcur, gh0, gh1, b, out, N);
}

// Round 11
// 88.897 us; speedup vs baseline: 1.0018x; 1.0018x over previous
//
#include <hip/hip_runtime.h>
#include <hip/hip_fp16.h>
#include <math.h>

constexpr int D = 64;           // D_IN == D_OUT == 64
constexpr int BNODES = 128;     // nodes per bucket
constexpr int BSHIFT = 7;
constexpr int BSTRIDE = 3072;   // fixed ebuf capacity per bucket (Poisson(2048) tail ~0)
constexpr int PCHUNK = 4096;    // edges per partition block
constexpr int NB_MAX = 1024;    // max buckets (N <= 131072)

typedef _Float16 half8 __attribute__((ext_vector_type(8)));
typedef float floatx4 __attribute__((ext_vector_type(4)));

// bcur[j] = j*BSTRIDE; Wt[j][k] = (f16) W[k][j]
__global__ __launch_bounds__(256) void k_init(const float* __restrict__ W,
                                              __half* __restrict__ Wt,
                                              int* __restrict__ bcur, int NB) {
    const int i = blockIdx.x * 256 + threadIdx.x;
    if (i < NB) bcur[i] = i * BSTRIDE;
    if (i < D * D) {
        const int j = i >> 6;
        const int k = i & 63;
        Wt[i] = __float2half(W[k * D + j]);
    }
}

// coarse partition into fixed-stride bucket segments; int4-vectorized edge reads.
__global__ __launch_bounds__(512) void k_partition(
        const int* __restrict__ ei, int* __restrict__ bcur,
        unsigned* __restrict__ ebuf, int E, int NB) {
    __shared__ int lh[NB_MAX];
    __shared__ int lb[NB_MAX];
    __shared__ int cc[PCHUNK];     // 16 KB c-cache
    const int t = threadIdx.x;
    for (int j = t; j < NB; j += 512) lh[j] = 0;
    __syncthreads();
    const int e0 = blockIdx.x * PCHUNK;
    const int e1 = min(e0 + PCHUNK, E);
    const bool full = (e1 - e0 == PCHUNK);

    if (full) {
        const int4* cp = reinterpret_cast<const int4*>(ei + E + e0);
        const int4 ca = cp[t];
        const int4 cb = cp[t + 512];
        reinterpret_cast<int4*>(cc)[t]       = ca;
        reinterpret_cast<int4*>(cc)[t + 512] = cb;
        atomicAdd(&lh[ca.x >> BSHIFT], 1); atomicAdd(&lh[ca.y >> BSHIFT], 1);
        atomicAdd(&lh[ca.z >> BSHIFT], 1); atomicAdd(&lh[ca.w >> BSHIFT], 1);
        atomicAdd(&lh[cb.x >> BSHIFT], 1); atomicAdd(&lh[cb.y >> BSHIFT], 1);
        atomicAdd(&lh[cb.z >> BSHIFT], 1); atomicAdd(&lh[cb.w >> BSHIFT], 1);
    } else {
        for (int e = e0 + t; e < e1; e += 512) {
            const int c = ei[E + e];
            cc[e - e0] = c;
            atomicAdd(&lh[c >> BSHIFT], 1);
        }
    }
    __syncthreads();
    for (int j = t; j < NB; j += 512) {
        const int n = lh[j];
        lb[j] = n ? atomicAdd(&bcur[j], n) : 0;
        lh[j] = 0;
    }
    __syncthreads();

    if (full) {
        const int4* rp = reinterpret_cast<const int4*>(ei + e0);
        const int4 ra = rp[t];
        const int4 rb = rp[t + 512];
        const int r8[8] = {ra.x, ra.y, ra.z, ra.w, rb.x, rb.y, rb.z, rb.w};
#pragma unroll
        for (int k = 0; k < 8; ++k) {
            const int ci = (k < 4) ? (4 * t + k) : (2048 + 4 * t + (k - 4));
            const int c = cc[ci];
            const int bkt = c >> BSHIFT;
            const int rank = atomicAdd(&lh[bkt], 1);
            const int pos = lb[bkt] + rank;
            if (pos < (bkt + 1) * BSTRIDE)
                ebuf[pos] = ((unsigned)r8[k] << BSHIFT) | (unsigned)(c & (BNODES - 1));
        }
    } else {
        for (int e = e0 + t; e < e1; e += 512) {
            const int r = ei[e];
            const int c = cc[e - e0];
            const int bkt = c >> BSHIFT;
            const int rank = atomicAdd(&lh[bkt], 1);
            const int pos = lb[bkt] + rank;
            if (pos < (bkt + 1) * BSTRIDE)
                ebuf[pos] = ((unsigned)r << BSHIFT) | (unsigned)(c & (BNODES - 1));
        }
    }
}

// fused per-bucket degree hist + MFMA GEMM: gh0/gh1(fp16 halves) = dinv * (x@W)
// One block per bucket (512 thr = 8 waves x 16-node tiles). No global cnt array.
__global__ __launch_bounds__(512) void k_gemm_fused(
        const float* __restrict__ x, const __half* __restrict__ Wt,
        const unsigned* __restrict__ ebuf, const int* __restrict__ bcur,
        __half* __restrict__ gh0, __half* __restrict__ gh1, int N) {
    __shared__ int lh[BNODES];
    const int j = blockIdx.x;
    const int t = threadIdx.x;
    const int base = j << BSHIFT;
    const int s0 = j * BSTRIDE;
    const int s1 = min(bcur[j], s0 + BSTRIDE);

    if (t < BNODES) lh[t] = 0;
    __syncthreads();
    for (int i = s0 + t; i < s1; i += 512)
        atomicAdd(&lh[ebuf[i] & (BNODES - 1)], 1);
    __syncthreads();

    const int wave = t >> 6;
    const int node16 = base + wave * 16;
    if (node16 >= N) return;          // N % 16 == 0, wave-aligned guard
    const int lane = t & 63;
    const int r16  = lane & 15;
    const int kq   = lane >> 4;

    const _Float16* wt = (const _Float16*)Wt;
    half8 bf[4][2];
#pragma unroll
    for (int jt = 0; jt < 4; ++jt)
#pragma unroll
        for (int s = 0; s < 2; ++s)
            bf[jt][s] = *(const half8*)(wt + (jt * 16 + r16) * D + s * 32 + kq * 8);

    half8 af[2];
#pragma unroll
    for (int s = 0; s < 2; ++s) {
        const float4* xp = reinterpret_cast<const float4*>(
            x + (size_t)(node16 + r16) * D + s * 32 + kq * 8);
        const float4 x0 = xp[0];
        const float4 x1 = xp[1];
        half8 a;
        a[0] = (_Float16)x0.x; a[1] = (_Float16)x0.y;
        a[2] = (_Float16)x0.z; a[3] = (_Float16)x0.w;
        a[4] = (_Float16)x1.x; a[5] = (_Float16)x1.y;
        a[6] = (_Float16)x1.z; a[7] = (_Float16)x1.w;
        af[s] = a;
    }

    floatx4 acc[4];
#pragma unroll
    for (int jt = 0; jt < 4; ++jt) {
        acc[jt] = (floatx4){0.f, 0.f, 0.f, 0.f};
        acc[jt] = __builtin_amdgcn_mfma_f32_16x16x32_f16(af[0], bf[jt][0], acc[jt], 0, 0, 0);
        acc[jt] = __builtin_amdgcn_mfma_f32_16x16x32_f16(af[1], bf[jt][1], acc[jt], 0, 0, 0);
    }

#pragma unroll
    for (int r = 0; r < 4; ++r) {
        const int nl = wave * 16 + kq * 4 + r;
        const int node = base + nl;
        const float dinv = rsqrtf((float)(lh[nl] + 1));
#pragma unroll
        for (int jt = 0; jt < 2; ++jt)
            gh0[(size_t)node * 32 + jt * 16 + r16] = __float2half(acc[jt][r] * dinv);
#pragma unroll
        for (int jt = 2; jt < 4; ++jt)
            gh1[(size_t)node * 32 + (jt - 2) * 16 + r16] = __float2half(acc[jt][r] * dinv);
    }
}

// fused per-bucket: LDS CSR build, then ONE 4-lane group per node per phase
// (4 lanes x 16B = 64B half-row). Two phases halve the gather working set.
__global__ __launch_bounds__(512) void k_breduce(
        const unsigned* __restrict__ ebuf, const int* __restrict__ bcur,
        const __half* __restrict__ gh0, const __half* __restrict__ gh1,
        const float* __restrict__ b, float* __restrict__ out, int N) {
    __shared__ int srcLDS[BSTRIDE];   // 12 KB
    __shared__ int lh[BNODES];
    __shared__ int st[BNODES];
    __shared__ int lcur[BNODES];
    const int j = blockIdx.x;
    const int t = threadIdx.x;
    const int s0 = j * BSTRIDE;
    const int s1 = min(bcur[j], s0 + BSTRIDE);
    const int base = j << BSHIFT;
    const int nn = min(BNODES, N - base);

    if (t < BNODES) lh[t] = 0;
    __syncthreads();
    for (int i = s0 + t; i < s1; i += 512)
        atomicAdd(&lh[ebuf[i] & (BNODES - 1)], 1);
    __syncthreads();
    if (t < BNODES) st[t] = lh[t];
    __syncthreads();
    for (int off = 1; off < BNODES; off <<= 1) {
        int y = 0;
        if (t < BNODES && t >= off) y = st[t - off];
        __syncthreads();
        if (t < BNODES && t >= off) st[t] += y;
        __syncthreads();
    }
    if (t < BNODES) {
        const int s = st[t] - lh[t];    // exclusive start (bucket-local)
        st[t] = s;
        lcur[t] = s;
    }
    __syncthreads();
    for (int i = s0 + t; i < s1; i += 512) {
        const unsigned code = ebuf[i];
        const int c = code & (BNODES - 1);
        const int rank = atomicAdd(&lcur[c], 1);
        srcLDS[rank] = (int)(code >> BSHIFT);
    }
    __syncthreads();

    const int g  = t >> 2;        // node 0..127
    const int fl = t & 3;         // 16B chunk of the 64B half-row
    if (g >= nn) return;

    const int node = base + g;
    const int start = st[g];
    const int num = lh[g];
    const float dinv = rsqrtf((float)(num + 1));
    const float4* b4 = reinterpret_cast<const float4*>(b);
    float4* o4 = reinterpret_cast<float4*>(out);
    const __half2 z = __float2half2_rn(0.f);

#pragma unroll
    for (int phase = 0; phase < 2; ++phase) {
        const uint4* gp = reinterpret_cast<const uint4*>(phase ? gh1 : gh0);

        // self-loop seed
        const uint4 su = gp[(size_t)node * 4 + fl];
        __half2 a0 = *(const __half2*)&su.x;
        __half2 a1 = *(const __half2*)&su.y;
        __half2 a2 = *(const __half2*)&su.z;
        __half2 a3 = *(const __half2*)&su.w;
        __half2 c0 = z, c1 = z, c2 = z, c3 = z;

        int i = start;
        const int end = start + num;
        for (; i + 2 <= end; i += 2) {      // 2 edges in flight
            const int r0 = srcLDS[i];
            const int r1 = srcLDS[i + 1];
            const uint4 u0 = gp[(size_t)r0 * 4 + fl];
            const uint4 u1 = gp[(size_t)r1 * 4 + fl];
            a0 = __hadd2(a0, *(const __half2*)&u0.x);
            a1 = __hadd2(a1, *(const __half2*)&u0.y);
            a2 = __hadd2(a2, *(const __half2*)&u0.z);
            a3 = __hadd2(a3, *(const __half2*)&u0.w);
            c0 = __hadd2(c0, *(const __half2*)&u1.x);
            c1 = __hadd2(c1, *(const __half2*)&u1.y);
            c2 = __hadd2(c2, *(const __half2*)&u1.z);
            c3 = __hadd2(c3, *(const __half2*)&u1.w);
        }
        if (i < end) {
            const int r = srcLDS[i];
            const uint4 u = gp[(size_t)r * 4 + fl];
            a0 = __hadd2(a0, *(const __half2*)&u.x);
            a1 = __hadd2(a1, *(const __half2*)&u.y);
            a2 = __hadd2(a2, *(const __half2*)&u.z);
            a3 = __hadd2(a3, *(const __half2*)&u.w);
        }
        a0 = __hadd2(a0, c0);
        a1 = __hadd2(a1, c1);
        a2 = __hadd2(a2, c2);
        a3 = __hadd2(a3, c3);

        const float2 f0 = __half22float2(a0);
        const float2 f1 = __half22float2(a1);
        const float2 f2 = __half22float2(a2);
        const float2 f3 = __half22float2(a3);
        const int ob = phase * 8 + fl * 2;   // float4 index of output cols
        const float4 bb0 = b4[ob];
        const float4 bb1 = b4[ob + 1];
        float4 o0, o1;
        o0.x = fmaf(dinv, f0.x, bb0.x); o0.y = fmaf(dinv, f0.y, bb0.y);
        o0.z = fmaf(dinv, f1.x, bb0.z); o0.w = fmaf(dinv, f1.y, bb0.w);
        o1.x = fmaf(dinv, f2.x, bb1.x); o1.y = fmaf(dinv, f2.y, bb1.y);
        o1.z = fmaf(dinv, f3.x, bb1.z); o1.w = fmaf(dinv, f3.y, bb1.w);
        o4[(size_t)node * 16 + ob]     = o0;
        o4[(size_t)node * 16 + ob + 1] = o1;
    }
}

extern "C" void kernel_launch(void* const* d_in, const int* in_sizes, int n_in,
                              void* d_out, int out_size, void* d_ws, size_t ws_size,
                              hipStream_t stream) {
    const float* x  = (const float*)d_in[0];
    const int*   ei = (const int*)d_in[1];
    const float* W  = (const float*)d_in[2];
    const float* b  = (const float*)d_in[3];
    float* out = (float*)d_out;

    const int N = in_sizes[0] / D;     // 100000
    const int E = in_sizes[1] / 2;     // 1600000
    const int NB = (N + BNODES - 1) >> BSHIFT;   // 782
    const int blocksP = (E + PCHUNK - 1) / PCHUNK;

    // ws layout (16B-aligned sections)
    __half*   gh0  = (__half*)d_ws;                     // N*32 halves (6.4 MB)
    __half*   gh1  = gh0 + (size_t)N * 32;              // N*32 halves (6.4 MB)
    __half*   Wt   = gh1 + (size_t)N * 32;              // 4096 halves (8 KB)
    unsigned* ebuf = (unsigned*)(Wt + D * D);           // NB*BSTRIDE (9.6 MB)
    int*      bcur = (int*)(ebuf + (size_t)NB * BSTRIDE); // NB

    k_init      <<<16, 256, 0, stream>>>(W, Wt, bcur, NB);
    k_partition <<<blocksP, 512, 0, stream>>>(ei, bcur, ebuf, E, NB);
    k_gemm_fused<<<NB, 512, 0, stream>>>(x, Wt, ebuf, bcur, gh0, gh1, N);
    k_breduce   <<<NB, 512, 0, stream>>>(ebuf, bcur, gh0, gh1, b, out, N);
}

// Round 12
// 78.896 us; speedup vs baseline: 1.1288x; 1.1268x over previous
//
#include <hip/hip_runtime.h>
#include <hip/hip_fp16.h>
#include <math.h>

constexpr int D = 64;           // D_IN == D_OUT == 64
constexpr int BNODES = 128;     // nodes per bucket
constexpr int BSHIFT = 7;
constexpr int BSTRIDE = 3072;   // fixed ebuf capacity per bucket (Poisson(2048) tail ~0)
constexpr int PCHUNK = 4096;    // edges per partition block
constexpr int NB_MAX = 1024;    // max buckets (N <= 131072)

typedef _Float16 half8 __attribute__((ext_vector_type(8)));
typedef float floatx4 __attribute__((ext_vector_type(4)));

// bcur[j] = j*BSTRIDE; Wt[j][k] = (f16) W[k][j]
__global__ __launch_bounds__(256) void k_init(const float* __restrict__ W,
                                              __half* __restrict__ Wt,
                                              int* __restrict__ bcur, int NB) {
    const int i = blockIdx.x * 256 + threadIdx.x;
    if (i < NB) bcur[i] = i * BSTRIDE;
    if (i < D * D) {
        const int j = i >> 6;
        const int k = i & 63;
        Wt[i] = __float2half(W[k * D + j]);
    }
}

// coarse partition into fixed-stride bucket segments; int4-vectorized edge reads.
__global__ __launch_bounds__(512) void k_partition(
        const int* __restrict__ ei, int* __restrict__ bcur,
        unsigned* __restrict__ ebuf, int E, int NB) {
    __shared__ int lh[NB_MAX];
    __shared__ int lb[NB_MAX];
    __shared__ int cc[PCHUNK];     // 16 KB c-cache
    const int t = threadIdx.x;
    for (int j = t; j < NB; j += 512) lh[j] = 0;
    __syncthreads();
    const int e0 = blockIdx.x * PCHUNK;
    const int e1 = min(e0 + PCHUNK, E);
    const bool full = (e1 - e0 == PCHUNK);

    if (full) {
        const int4* cp = reinterpret_cast<const int4*>(ei + E + e0);
        const int4 ca = cp[t];
        const int4 cb = cp[t + 512];
        reinterpret_cast<int4*>(cc)[t]       = ca;
        reinterpret_cast<int4*>(cc)[t + 512] = cb;
        atomicAdd(&lh[ca.x >> BSHIFT], 1); atomicAdd(&lh[ca.y >> BSHIFT], 1);
        atomicAdd(&lh[ca.z >> BSHIFT], 1); atomicAdd(&lh[ca.w >> BSHIFT], 1);
        atomicAdd(&lh[cb.x >> BSHIFT], 1); atomicAdd(&lh[cb.y >> BSHIFT], 1);
        atomicAdd(&lh[cb.z >> BSHIFT], 1); atomicAdd(&lh[cb.w >> BSHIFT], 1);
    } else {
        for (int e = e0 + t; e < e1; e += 512) {
            const int c = ei[E + e];
            cc[e - e0] = c;
            atomicAdd(&lh[c >> BSHIFT], 1);
        }
    }
    __syncthreads();
    for (int j = t; j < NB; j += 512) {
        const int n = lh[j];
        lb[j] = n ? atomicAdd(&bcur[j], n) : 0;
        lh[j] = 0;
    }
    __syncthreads();

    if (full) {
        const int4* rp = reinterpret_cast<const int4*>(ei + e0);
        const int4 ra = rp[t];
        const int4 rb = rp[t + 512];
        const int r8[8] = {ra.x, ra.y, ra.z, ra.w, rb.x, rb.y, rb.z, rb.w};
#pragma unroll
        for (int k = 0; k < 8; ++k) {
            const int ci = (k < 4) ? (4 * t + k) : (2048 + 4 * t + (k - 4));
            const int c = cc[ci];
            const int bkt = c >> BSHIFT;
            const int rank = atomicAdd(&lh[bkt], 1);
            const int pos = lb[bkt] + rank;
            if (pos < (bkt + 1) * BSTRIDE)
                ebuf[pos] = ((unsigned)r8[k] << BSHIFT) | (unsigned)(c & (BNODES - 1));
        }
    } else {
        for (int e = e0 + t; e < e1; e += 512) {
            const int r = ei[e];
            const int c = cc[e - e0];
            const int bkt = c >> BSHIFT;
            const int rank = atomicAdd(&lh[bkt], 1);
            const int pos = lb[bkt] + rank;
            if (pos < (bkt + 1) * BSTRIDE)
                ebuf[pos] = ((unsigned)r << BSHIFT) | (unsigned)(c & (BNODES - 1));
        }
    }
}

// fused per-bucket degree hist + MFMA GEMM: gh(fp16 [N][64]) = dinv * (x@W)
// One block per bucket (512 thr = 8 waves x 16-node tiles). No global cnt array.
__global__ __launch_bounds__(512) void k_gemm_fused(
        const float* __restrict__ x, const __half* __restrict__ Wt,
        const unsigned* __restrict__ ebuf, const int* __restrict__ bcur,
        __half* __restrict__ gh, int N) {
    __shared__ int lh[BNODES];
    const int j = blockIdx.x;
    const int t = threadIdx.x;
    const int base = j << BSHIFT;
    const int s0 = j * BSTRIDE;
    const int s1 = min(bcur[j], s0 + BSTRIDE);

    if (t < BNODES) lh[t] = 0;
    __syncthreads();
    for (int i = s0 + t; i < s1; i += 512)
        atomicAdd(&lh[ebuf[i] & (BNODES - 1)], 1);
    __syncthreads();

    const int wave = t >> 6;
    const int node16 = base + wave * 16;
    if (node16 >= N) return;          // N % 16 == 0, wave-aligned guard
    const int lane = t & 63;
    const int r16  = lane & 15;
    const int kq   = lane >> 4;

    const _Float16* wt = (const _Float16*)Wt;
    half8 bf[4][2];
#pragma unroll
    for (int jt = 0; jt < 4; ++jt)
#pragma unroll
        for (int s = 0; s < 2; ++s)
            bf[jt][s] = *(const half8*)(wt + (jt * 16 + r16) * D + s * 32 + kq * 8);

    half8 af[2];
#pragma unroll
    for (int s = 0; s < 2; ++s) {
        const float4* xp = reinterpret_cast<const float4*>(
            x + (size_t)(node16 + r16) * D + s * 32 + kq * 8);
        const float4 x0 = xp[0];
        const float4 x1 = xp[1];
        half8 a;
        a[0] = (_Float16)x0.x; a[1] = (_Float16)x0.y;
        a[2] = (_Float16)x0.z; a[3] = (_Float16)x0.w;
        a[4] = (_Float16)x1.x; a[5] = (_Float16)x1.y;
        a[6] = (_Float16)x1.z; a[7] = (_Float16)x1.w;
        af[s] = a;
    }

    floatx4 acc[4];
#pragma unroll
    for (int jt = 0; jt < 4; ++jt) {
        acc[jt] = (floatx4){0.f, 0.f, 0.f, 0.f};
        acc[jt] = __builtin_amdgcn_mfma_f32_16x16x32_f16(af[0], bf[jt][0], acc[jt], 0, 0, 0);
        acc[jt] = __builtin_amdgcn_mfma_f32_16x16x32_f16(af[1], bf[jt][1], acc[jt], 0, 0, 0);
    }

#pragma unroll
    for (int r = 0; r < 4; ++r) {
        const int nl = wave * 16 + kq * 4 + r;
        const int node = base + nl;
        const float dinv = rsqrtf((float)(lh[nl] + 1));
#pragma unroll
        for (int jt = 0; jt < 4; ++jt)
            gh[(size_t)node * D + jt * 16 + r16] = __float2half(acc[jt][r] * dinv);
    }
}

// fused per-bucket: LDS CSR build (wave-scan), then ONE 8-lane group per node
// (8 lanes x 16B = full 128B row); 4 edges in flight per group.
__global__ __launch_bounds__(512) void k_breduce(
        const unsigned* __restrict__ ebuf, const int* __restrict__ bcur,
        const __half* __restrict__ gh, const float* __restrict__ b,
        float* __restrict__ out, int N) {
    __shared__ int srcLDS[BSTRIDE];   // 12 KB
    __shared__ int lh[BNODES];
    __shared__ int st[BNODES];
    __shared__ int lcur[BNODES];
    const int j = blockIdx.x;
    const int t = threadIdx.x;
    const int s0 = j * BSTRIDE;
    const int s1 = min(bcur[j], s0 + BSTRIDE);
    const int base = j << BSHIFT;
    const int nn = min(BNODES, N - base);

    if (t < BNODES) lh[t] = 0;
    __syncthreads();
    for (int i = s0 + t; i < s1; i += 512)
        atomicAdd(&lh[ebuf[i] & (BNODES - 1)], 1);
    __syncthreads();
    // single-wave exclusive scan of the 128 degrees (2 per lane, shfl_up)
    if (t < 64) {
        const int v0 = lh[2 * t];
        const int v1 = lh[2 * t + 1];
        int s = v0 + v1;
#pragma unroll
        for (int off = 1; off < 64; off <<= 1) {
            const int y = __shfl_up(s, off, 64);
            if (t >= off) s += y;
        }
        const int excl = s - (v0 + v1);
        st[2 * t] = excl;         st[2 * t + 1] = excl + v0;
        lcur[2 * t] = excl;       lcur[2 * t + 1] = excl + v0;
    }
    __syncthreads();
    for (int i = s0 + t; i < s1; i += 512) {
        const unsigned code = ebuf[i];
        const int c = code & (BNODES - 1);
        const int rank = atomicAdd(&lcur[c], 1);
        srcLDS[rank] = (int)(code >> BSHIFT);
    }
    __syncthreads();

    const int g8 = t >> 3;        // group 0..63, one node at a time
    const int fl = t & 7;         // 16B chunk of the 128B row

    const uint4* g4 = reinterpret_cast<const uint4*>(gh);
    const float4* b4 = reinterpret_cast<const float4*>(b);
    float4* o4 = reinterpret_cast<float4*>(out);
    const __half2 z = __float2half2_rn(0.f);
    const float4 bb0 = b4[fl * 2];
    const float4 bb1 = b4[fl * 2 + 1];

#pragma unroll
    for (int q = 0; q < 2; ++q) {
        const int nl = q * 64 + g8;
        if (nl >= nn) continue;
        const int node = base + nl;
        const int start = st[nl];
        const int num = lh[nl];

        // self-loop seed + three zero accumulator sets
        const uint4 su = g4[(size_t)node * 8 + fl];
        __half2 a0 = *(const __half2*)&su.x, a1 = *(const __half2*)&su.y;
        __half2 a2 = *(const __half2*)&su.z, a3 = *(const __half2*)&su.w;
        __half2 p0 = z, p1 = z, p2 = z, p3 = z;
        __half2 q0 = z, q1 = z, q2 = z, q3 = z;
        __half2 s0h = z, s1h = z, s2h = z, s3h = z;

        int i = start;
        const int end = start + num;
        for (; i + 4 <= end; i += 4) {      // 4 edges in flight
            const int r0 = srcLDS[i];
            const int r1 = srcLDS[i + 1];
            const int r2 = srcLDS[i + 2];
            const int r3 = srcLDS[i + 3];
            const uint4 u0 = g4[(size_t)r0 * 8 + fl];
            const uint4 u1 = g4[(size_t)r1 * 8 + fl];
            const uint4 u2 = g4[(size_t)r2 * 8 + fl];
            const uint4 u3 = g4[(size_t)r3 * 8 + fl];
            a0 = __hadd2(a0, *(const __half2*)&u0.x);
            a1 = __hadd2(a1, *(const __half2*)&u0.y);
            a2 = __hadd2(a2, *(const __half2*)&u0.z);
            a3 = __hadd2(a3, *(const __half2*)&u0.w);
            p0 = __hadd2(p0, *(const __half2*)&u1.x);
            p1 = __hadd2(p1, *(const __half2*)&u1.y);
            p2 = __hadd2(p2, *(const __half2*)&u1.z);
            p3 = __hadd2(p3, *(const __half2*)&u1.w);
            q0 = __hadd2(q0, *(const __half2*)&u2.x);
            q1 = __hadd2(q1, *(const __half2*)&u2.y);
            q2 = __hadd2(q2, *(const __half2*)&u2.z);
            q3 = __hadd2(q3, *(const __half2*)&u2.w);
            s0h = __hadd2(s0h, *(const __half2*)&u3.x);
            s1h = __hadd2(s1h, *(const __half2*)&u3.y);
            s2h = __hadd2(s2h, *(const __half2*)&u3.z);
            s3h = __hadd2(s3h, *(const __half2*)&u3.w);
        }
        for (; i < end; ++i) {
            const int r = srcLDS[i];
            const uint4 u = g4[(size_t)r * 8 + fl];
            a0 = __hadd2(a0, *(const __half2*)&u.x);
            a1 = __hadd2(a1, *(const __half2*)&u.y);
            a2 = __hadd2(a2, *(const __half2*)&u.z);
            a3 = __hadd2(a3, *(const __half2*)&u.w);
        }
        a0 = __hadd2(__hadd2(a0, p0), __hadd2(q0, s0h));
        a1 = __hadd2(__hadd2(a1, p1), __hadd2(q1, s1h));
        a2 = __hadd2(__hadd2(a2, p2), __hadd2(q2, s2h));
        a3 = __hadd2(__hadd2(a3, p3), __hadd2(q3, s3h));

        const float dinv = rsqrtf((float)(num + 1));
        const float2 f0 = __half22float2(a0);
        const float2 f1 = __half22float2(a1);
        const float2 f2 = __half22float2(a2);
        const float2 f3 = __half22float2(a3);
        float4 o0, o1;
        o0.x = fmaf(dinv, f0.x, bb0.x); o0.y = fmaf(dinv, f0.y, bb0.y);
        o0.z = fmaf(dinv, f1.x, bb0.z); o0.w = fmaf(dinv, f1.y, bb0.w);
        o1.x = fmaf(dinv, f2.x, bb1.x); o1.y = fmaf(dinv, f2.y, bb1.y);
        o1.z = fmaf(dinv, f3.x, bb1.z); o1.w = fmaf(dinv, f3.y, bb1.w);
        o4[(size_t)node * 16 + fl * 2]     = o0;
        o4[(size_t)node * 16 + fl * 2 + 1] = o1;
    }
}

extern "C" void kernel_launch(void* const* d_in, const int* in_sizes, int n_in,
                              void* d_out, int out_size, void* d_ws, size_t ws_size,
                              hipStream_t stream) {
    const float* x  = (const float*)d_in[0];
    const int*   ei = (const int*)d_in[1];
    const float* W  = (const float*)d_in[2];
    const float* b  = (const float*)d_in[3];
    float* out = (float*)d_out;

    const int N = in_sizes[0] / D;     // 100000
    const int E = in_sizes[1] / 2;     // 1600000
    const int NB = (N + BNODES - 1) >> BSHIFT;   // 782
    const int blocksP = (E + PCHUNK - 1) / PCHUNK;

    // ws layout (16B-aligned sections)
    __half*   gh   = (__half*)d_ws;                     // N*64 halves (12.8 MB)
    __half*   Wt   = gh + (size_t)N * D;                // 4096 halves (8 KB)
    unsigned* ebuf = (unsigned*)(Wt + D * D);           // NB*BSTRIDE (9.6 MB)
    int*      bcur = (int*)(ebuf + (size_t)NB * BSTRIDE); // NB

    k_init      <<<16, 256, 0, stream>>>(W, Wt, bcur, NB);
    k_partition <<<blocksP, 512, 0, stream>>>(ei, bcur, ebuf, E, NB);
    k_gemm_fused<<<NB, 512, 0, stream>>>(x, Wt, ebuf, bcur, gh, N);
    k_breduce   <<<NB, 512, 0, stream>>>(ebuf, bcur, gh, b, out, N);
}